// Round 1
// 228.248 us; speedup vs baseline: 1.7677x; 1.7677x over previous
//
#include <hip/hip_runtime.h>

#define N_ROWS 8192
#define DIMS   256

typedef __attribute__((ext_vector_type(8)))  short bf16x8;
typedef __attribute__((ext_vector_type(16))) float f32x16;

// ws layout:
// [0, 32768)        : float sq[8192]
// [32768, 33792)    : float colsum[256]        (zeroed each launch)
// [33792, ...)      : Scalars                  (zeroed each launch)
struct Scalars {
    double result;        // atomic double accumulator
    float  sumsq;         // atomic float accumulator
    unsigned int n0;      // atomic count of sub==0
    float  c2;            // -log2(e) / (16*bw)
    float  w0;            // +1/n0
    float  w1;            // -1/n1
};

// ---------------------------------------------------------------- K1: row/col stats
__global__ __launch_bounds__(256) void k1_rows(const float* __restrict__ x,
                                               const long long* __restrict__ sub,
                                               float* __restrict__ sq,
                                               float* __restrict__ colsum,
                                               Scalars* sc) {
    const int t    = threadIdx.x;
    const int lane = t & 63;
    const int wave = t >> 6;
    const int rowbase = blockIdx.x * 64 + wave * 16;

    float4 colacc = make_float4(0.f, 0.f, 0.f, 0.f);
    float  my_sumsq = 0.f;

    for (int r = 0; r < 16; ++r) {
        const int row = rowbase + r;
        const float4 v = ((const float4*)(x + (size_t)row * DIMS))[lane];
        colacc.x += v.x; colacc.y += v.y; colacc.z += v.z; colacc.w += v.w;
        float s = v.x * v.x + v.y * v.y + v.z * v.z + v.w * v.w;
        #pragma unroll
        for (int off = 32; off; off >>= 1) s += __shfl_down(s, off, 64);
        if (lane == 0) { sq[row] = s; my_sumsq += s; }
    }
    if (lane == 0) atomicAdd(&sc->sumsq, my_sumsq);

    const int d = lane * 4;
    atomicAdd(&colsum[d + 0], colacc.x);
    atomicAdd(&colsum[d + 1], colacc.y);
    atomicAdd(&colsum[d + 2], colacc.z);
    atomicAdd(&colsum[d + 3], colacc.w);

    if (wave == 0) {
        const int row = blockIdx.x * 64 + lane;
        const int v = (int)sub[row];
        unsigned long long mask = __ballot(v == 0);
        if (lane == 0) atomicAdd(&sc->n0, (unsigned int)__popcll(mask));
    }
}

// ---------------------------------------------------------------- K2: bandwidth & weights
__global__ __launch_bounds__(64) void k2_scalars(const float* __restrict__ colsum,
                                                 Scalars* sc) {
    const int lane = threadIdx.x;
    const float4 c = ((const float4*)colsum)[lane];
    float ss = c.x * c.x + c.y * c.y + c.z * c.z + c.w * c.w;
    #pragma unroll
    for (int off = 32; off; off >>= 1) ss += __shfl_down(ss, off, 64);
    if (lane == 0) {
        const double n = (double)N_ROWS;
        // sum(L2) = 2n*sum(sq) - 2*||colsum||^2  (diag clamp negligible: <1e-9 rel)
        const double sumL2 = 2.0 * n * (double)sc->sumsq - 2.0 * (double)ss;
        const double bw = sumL2 / (n * n - n) / 4.0;   // / KERNEL_MUL^(KERNEL_NUM/2)
        sc->c2 = (float)(-1.4426950408889634 / (16.0 * bw));
        const double n0 = (double)sc->n0;
        const double n1 = n - n0;
        sc->w0 = (float)( 1.0 / n0);
        sc->w1 = (float)(-1.0 / n1);
    }
}

// ---------------------------------------------------------------- split fp32 -> bf16 hi/lo, write both LDS planes
// hi = truncate(x) (top 16 bits), lo = truncate(x - hi). Dropped lo*lo term is
// ~2^-16 relative; constant component cancels exactly in the MMD weighted sum.
__device__ __forceinline__ void split_write(short* hbase, const float4 v) {
    const unsigned bx = __float_as_uint(v.x) & 0xffff0000u;
    const unsigned by = __float_as_uint(v.y) & 0xffff0000u;
    const unsigned bz = __float_as_uint(v.z) & 0xffff0000u;
    const unsigned bw = __float_as_uint(v.w) & 0xffff0000u;
    uint2 hw;
    hw.x = (bx >> 16) | by;
    hw.y = (bz >> 16) | bw;
    const float lx = v.x - __uint_as_float(bx);
    const float ly = v.y - __uint_as_float(by);
    const float lz = v.z - __uint_as_float(bz);
    const float lw = v.w - __uint_as_float(bw);
    uint2 lo;
    lo.x = __builtin_amdgcn_perm(__float_as_uint(ly), __float_as_uint(lx), 0x07060302u);
    lo.y = __builtin_amdgcn_perm(__float_as_uint(lw), __float_as_uint(lz), 0x07060302u);
    *(uint2*)(hbase)        = hw;   // hi plane
    *(uint2*)(hbase + 4096) = lo;   // lo plane (+4096 shorts)
}

// ---------------------------------------------------------------- K3: MFMA Gram + kernel + reduce
// 128x128 tile, 4 waves x (64x64 as 2x2 mfma_f32_32x32x16_bf16 frags), BK=32,
// split-bf16 3-pass (HH + HL + LH), double-buffered LDS (2 x 32KB = 64KB).
// LDS layout per buffer (shorts): Ahi[0) Alo[4096) Bhi[8192) Blo[12288);
// within a plane: region(ks,rowblk)=( (ks*4+rowblk)*512 ), lane-linear 8 shorts/lane
// so fragment reads are contiguous 16B/lane (conflict-free).
__global__ __launch_bounds__(256, 2) void k3_mmd(const float* __restrict__ x,
                                                 const long long* __restrict__ sub,
                                                 const float* __restrict__ sq,
                                                 Scalars* sc) {
    const int bi = blockIdx.y;   // row tile
    const int bj = blockIdx.x;   // col tile
    if (bj < bi) return;         // upper triangle only (uniform exit)

    __shared__ short lds[32768];   // exactly 64 KB

    const int t  = threadIdx.x;
    const int l  = t & 63;
    const int w  = t >> 6;
    const int wr = w >> 1;       // wave row (0..1)
    const int wc = w & 1;        // wave col (0..1)

    // staging: thread t owns row (t>>3)+32*i, k-quad (t&7)*4 of the 128x32 chunk
    const int row8 = t >> 3;
    const int kc4  = (t & 7) << 2;
    const int wb   = ((kc4 >> 4) << 11) + ((row8 + ((kc4 >> 3) & 1) * 32) << 3) + (kc4 & 7);

    const float* gA = x + (size_t)(bi * 128 + row8) * DIMS + kc4;
    const float* gB = x + (size_t)(bj * 128 + row8) * DIMS + kc4;

    f32x16 acc[2][2] = {};
    float4 ra[4], rb[4];

    auto load_regs = [&](int c) {
        const int kg = c << 5;
        #pragma unroll
        for (int i = 0; i < 4; ++i) {
            ra[i] = *(const float4*)(gA + i * (32 * DIMS) + kg);
            rb[i] = *(const float4*)(gB + i * (32 * DIMS) + kg);
        }
    };
    auto cvt_store = [&](int bufb) {
        #pragma unroll
        for (int i = 0; i < 4; ++i) {
            split_write(&lds[bufb + wb + i * 512], ra[i]);
            split_write(&lds[bufb + 8192 + wb + i * 512], rb[i]);
        }
    };
    auto compute = [&](int bufb) {
        #pragma unroll
        for (int ks = 0; ks < 2; ++ks) {
            bf16x8 ah[2], al[2], bh[2], bl[2];
            #pragma unroll
            for (int m = 0; m < 2; ++m) {
                const int ao = bufb + ((ks * 4 + wr * 2 + m) << 9) + (l << 3);
                ah[m] = *(const bf16x8*)&lds[ao];
                al[m] = *(const bf16x8*)&lds[ao + 4096];
            }
            #pragma unroll
            for (int n = 0; n < 2; ++n) {
                const int bo = bufb + 8192 + ((ks * 4 + wc * 2 + n) << 9) + (l << 3);
                bh[n] = *(const bf16x8*)&lds[bo];
                bl[n] = *(const bf16x8*)&lds[bo + 4096];
            }
            #pragma unroll
            for (int m = 0; m < 2; ++m)
                #pragma unroll
                for (int n = 0; n < 2; ++n) {
                    acc[m][n] = __builtin_amdgcn_mfma_f32_32x32x16_bf16(ah[m], bh[n], acc[m][n], 0, 0, 0);
                    acc[m][n] = __builtin_amdgcn_mfma_f32_32x32x16_bf16(ah[m], bl[n], acc[m][n], 0, 0, 0);
                    acc[m][n] = __builtin_amdgcn_mfma_f32_32x32x16_bf16(al[m], bh[n], acc[m][n], 0, 0, 0);
                }
        }
    };

    // prologue: fill buffer 0
    load_regs(0);
    cvt_store(0);
    __syncthreads();

    #pragma unroll 2
    for (int c = 0; c < 8; ++c) {
        if (c < 7) load_regs(c + 1);             // issue-early (latency hides under MFMA)
        compute((c & 1) << 14);
        if (c < 7) cvt_store(((c + 1) & 1) << 14);  // write-late into the other buffer
        __syncthreads();
    }

    // ---------------- epilogue: L2 -> multi-scale kernel -> weighted partial sum
    const float c2 = sc->c2, w0 = sc->w0, w1 = sc->w1;
    const int lh  = l >> 5;
    const int ln  = l & 31;
    const int itb = bi * 128 + wr * 64;
    const int jtb = bj * 128 + wc * 64;

    float sqJ[2], wJ[2];
    #pragma unroll
    for (int n = 0; n < 2; ++n) {
        const int J = jtb + n * 32 + ln;
        sqJ[n] = sq[J];
        wJ[n]  = ((int)sub[J] == 0) ? w0 : w1;
    }

    float part = 0.f;
    const bool diag = (bi == bj);
    #pragma unroll
    for (int m = 0; m < 2; ++m) {
        #pragma unroll
        for (int r = 0; r < 16; ++r) {
            // verified C/D layout: col = lane&31, row = (r&3) + 8*(r>>2) + 4*(lane>>5)
            const int I = itb + m * 32 + (r & 3) + ((r >> 2) << 3) + (lh << 2);
            const float sqi = sq[I];
            const float wi  = ((int)sub[I] == 0) ? w0 : w1;
            #pragma unroll
            for (int n = 0; n < 2; ++n) {
                const float g = acc[m][n][r];
                float l2 = fmaxf(sqi + sqJ[n] - 2.f * g, 0.f);
                const float tt  = exp2f(l2 * c2);           // exp(-L2/(16*bw))
                const float t2  = tt * tt;
                const float t4  = t2 * t2;
                const float t8  = t4 * t4;
                const float t16 = t8 * t8;
                const float K   = tt + t2 + t4 + t8 + t16;
                float f = 2.f;
                if (diag) {
                    const int J = jtb + n * 32 + ln;
                    f = (I < J) ? 2.f : ((I == J) ? 1.f : 0.f);
                }
                part += f * wi * wJ[n] * K;
            }
        }
    }

    // block reduction (reuse LDS: all tile reads are behind the final barrier)
    float* red = (float*)lds;
    red[t] = part;
    __syncthreads();
    #pragma unroll
    for (int s = 128; s; s >>= 1) {
        if (t < s) red[t] += red[t + s];
        __syncthreads();
    }
    if (t == 0) atomicAdd(&sc->result, (double)red[0]);
}

// ---------------------------------------------------------------- K4: emit scalar
__global__ void k4_write(const Scalars* sc, float* out) {
    if (threadIdx.x == 0) out[0] = (float)sc->result;
}

extern "C" void kernel_launch(void* const* d_in, const int* in_sizes, int n_in,
                              void* d_out, int out_size, void* d_ws, size_t ws_size,
                              hipStream_t stream) {
    const long long* sub = (const long long*)d_in[0];   // subggroup int64 (N,1)
    const float*     x   = (const float*)d_in[1];       // outputs fp32 (N,256)
    float* out = (float*)d_out;

    char* ws = (char*)d_ws;
    float*   sq     = (float*)ws;
    float*   colsum = (float*)(ws + 32768);
    Scalars* sc     = (Scalars*)(ws + 33792);

    // zero the accumulators (colsum + scalars); sq is fully overwritten
    hipMemsetAsync(ws + 32768, 0, 2048, stream);

    k1_rows<<<N_ROWS / 64, 256, 0, stream>>>(x, sub, sq, colsum, sc);
    k2_scalars<<<1, 64, 0, stream>>>(colsum, sc);

    dim3 g3(64, 64);
    k3_mmd<<<g3, 256, 0, stream>>>(x, sub, sq, sc);

    k4_write<<<1, 64, 0, stream>>>(sc, out);
}

// Round 2
// 152.294 us; speedup vs baseline: 2.6493x; 1.4987x over previous
//
#include <hip/hip_runtime.h>

#define N_ROWS 8192
#define DIMS   256

typedef _Float16 f16x4 __attribute__((ext_vector_type(4)));
typedef _Float16 f16x8 __attribute__((ext_vector_type(8)));
typedef float   f32x16 __attribute__((ext_vector_type(16)));

// ws layout:
// [0, 32768)        : float sq[8192]
// [32768, 33792)    : float colsum[256]        (zeroed each launch)
// [33792, 36864)    : Scalars                  (zeroed each launch)
// [36864, 36864+4M) : fp16 plane of x, MFMA-fragment-permuted:
//                     [rowblk=row/32][ks=k/16][slot=(row%32)+32*((k%16)/8)][(k%8)]
struct Scalars {
    double result;        // atomic double accumulator
    float  sumsq;         // atomic float accumulator
    unsigned int n0;      // atomic count of sub==0
    float  c2;            // -log2(e) / (16*bw)
    float  w0;            // +1/n0
    float  w1;            // -1/n1
};

// ---------------------------------------------------------------- K1: stats + fp16 plane emit
// 256 blocks x 256 threads; block handles 32 rows, each wave 8 rows.
__global__ __launch_bounds__(256) void k1_rows(const float* __restrict__ x,
                                               const long long* __restrict__ sub,
                                               float* __restrict__ sq,
                                               float* __restrict__ colsum,
                                               unsigned short* __restrict__ plane,
                                               Scalars* sc) {
    __shared__ float cls[4][256];
    const int t = threadIdx.x;
    const int l = t & 63;
    const int w = t >> 6;
    const int base = blockIdx.x * 32;

    float4 colacc = make_float4(0.f, 0.f, 0.f, 0.f);
    float  my_sumsq = 0.f;

    // plane dest components that only depend on lane
    const int ks  = l >> 2;
    const int s16 = l & 3;
    const int lslot_add = ((s16 >> 1) << 5);
    const int lhalf_add = (s16 & 1) * 4;

    #pragma unroll
    for (int r = 0; r < 8; ++r) {
        const int row = base + w * 8 + r;
        const float4 v = ((const float4*)(x + (size_t)row * DIMS))[l];
        colacc.x += v.x; colacc.y += v.y; colacc.z += v.z; colacc.w += v.w;

        // emit fp16 plane in fragment-permuted layout (RNE)
        const size_t hidx = ((size_t)(row >> 5) * 16 + ks) * 512
                          + (size_t)(((row & 31) + lslot_add) * 8 + lhalf_add);
        f16x4 h = { (_Float16)v.x, (_Float16)v.y, (_Float16)v.z, (_Float16)v.w };
        *(f16x4*)(plane + hidx) = h;

        float s = v.x * v.x + v.y * v.y + v.z * v.z + v.w * v.w;
        #pragma unroll
        for (int off = 32; off; off >>= 1) s += __shfl_down(s, off, 64);
        if (l == 0) { sq[row] = s; my_sumsq += s; }
    }
    if (l == 0) atomicAdd(&sc->sumsq, my_sumsq);

    // block-reduce colsum, one atomic per column per block
    *(float4*)&cls[w][l * 4] = colacc;
    __syncthreads();
    {
        const float ssum = cls[0][t] + cls[1][t] + cls[2][t] + cls[3][t];
        atomicAdd(&colsum[t], ssum);
    }

    if (w == 0) {
        const int vv = (l < 32) ? (int)sub[base + (l & 31)] : 1;
        unsigned long long mask = __ballot(vv == 0);
        if (l == 0) atomicAdd(&sc->n0, (unsigned int)__popcll(mask));
    }
}

// ---------------------------------------------------------------- K2: bandwidth & weights
__global__ __launch_bounds__(64) void k2_scalars(const float* __restrict__ colsum,
                                                 Scalars* sc) {
    const int lane = threadIdx.x;
    const float4 c = ((const float4*)colsum)[lane];
    float ss = c.x * c.x + c.y * c.y + c.z * c.z + c.w * c.w;
    #pragma unroll
    for (int off = 32; off; off >>= 1) ss += __shfl_down(ss, off, 64);
    if (lane == 0) {
        const double n = (double)N_ROWS;
        // sum(L2) = 2n*sum(sq) - 2*||colsum||^2  (diag clamp negligible)
        const double sumL2 = 2.0 * n * (double)sc->sumsq - 2.0 * (double)ss;
        const double bw = sumL2 / (n * n - n) / 4.0;   // / KERNEL_MUL^(KERNEL_NUM/2)
        sc->c2 = (float)(-1.4426950408889634 / (16.0 * bw));
        const double n0 = (double)sc->n0;
        const double n1 = n - n0;
        sc->w0 = (float)( 1.0 / n0);
        sc->w1 = (float)(-1.0 / n1);
    }
}

// ---------------------------------------------------------------- K3: fp16 MFMA Gram + kernel + reduce
// Block tile 256x128, 4 waves (2x2), wave tile 128x64 = 4x2 frags of 32x32x16_f16.
// BK=32 (2 ks per chunk), double-buffered 2x24KB LDS, staged via global_load_lds
// from the pre-permuted fp16 plane (regions of 1KB are contiguous in global).
__global__ __launch_bounds__(256, 2) void k3_mmd(const unsigned short* __restrict__ plane,
                                                 const long long* __restrict__ sub,
                                                 const float* __restrict__ sq,
                                                 Scalars* sc) {
    const int bi = blockIdx.y;   // row tile (256 rows)
    const int bj = blockIdx.x;   // col tile (128 cols)
    if (bj < 2 * bi) return;     // upper triangle only (uniform exit)

    __shared__ char lds[49152];  // 2 x (A 16KB + B 8KB)

    const int t  = threadIdx.x;
    const int l  = t & 63;
    const int w  = t >> 6;
    const int wr = w >> 1;       // wave row (0..1)
    const int wc = w & 1;        // wave col (0..1)

    f32x16 acc[4][2] = {};

    // stage chunk (ks pair kbase,kbase+1) into buffer at byte offset bufb.
    // 24 regions x 1KB; wave w stages regions [w*6, w*6+6).
    auto stage = [&](int kbase, int bufb) {
        #pragma unroll
        for (int i = 0; i < 6; ++i) {
            const int id = w * 6 + i;
            size_t grb;
            if (id < 16) {
                grb = (size_t)((bi * 8 + (id >> 1)) * 16 + kbase + (id & 1));
            } else {
                const int idb = id - 16;
                grb = (size_t)((bj * 4 + (idb >> 1)) * 16 + kbase + (idb & 1));
            }
            const unsigned short* g = plane + grb * 512 + l * 8;   // 16B per lane
            char* lp = lds + bufb + id * 1024;                     // wave-uniform dest
            __builtin_amdgcn_global_load_lds(
                (const __attribute__((address_space(1))) unsigned int*)(const void*)g,
                (__attribute__((address_space(3))) unsigned int*)(void*)lp, 16, 0, 0);
        }
    };

    auto compute = [&](int bufb) {
        #pragma unroll
        for (int ksL = 0; ksL < 2; ++ksL) {
            f16x8 a[4], b[2];
            #pragma unroll
            for (int m = 0; m < 4; ++m)
                a[m] = *(const f16x8*)(lds + bufb + ((wr * 4 + m) * 2 + ksL) * 1024 + l * 16);
            #pragma unroll
            for (int n = 0; n < 2; ++n)
                b[n] = *(const f16x8*)(lds + bufb + 16384 + ((wc * 2 + n) * 2 + ksL) * 1024 + l * 16);
            #pragma unroll
            for (int m = 0; m < 4; ++m)
                #pragma unroll
                for (int n = 0; n < 2; ++n)
                    acc[m][n] = __builtin_amdgcn_mfma_f32_32x32x16_f16(a[m], b[n], acc[m][n], 0, 0, 0);
        }
    };

    stage(0, 0);
    __syncthreads();

    for (int c = 0; c < 8; ++c) {
        const int cur = (c & 1) * 24576;
        if (c < 7) stage((c + 1) * 2, ((c + 1) & 1) * 24576);  // prefetch flies under compute
        compute(cur);
        __syncthreads();   // drains vmcnt+lgkmcnt: prefetch landed, reads done
    }

    // ---------------- epilogue: L2 -> multi-scale kernel -> weighted partial sum
    const float c2 = sc->c2, w0 = sc->w0, w1 = sc->w1;
    const int lh  = l >> 5;
    const int ln  = l & 31;
    const int itb = bi * 256 + wr * 128;
    const int jtb = bj * 128 + wc * 64;

    float sqJ[2], wJ[2];
    #pragma unroll
    for (int n = 0; n < 2; ++n) {
        const int J = jtb + n * 32 + ln;
        sqJ[n] = sq[J];
        wJ[n]  = ((int)sub[J] == 0) ? w0 : w1;
    }

    float part = 0.f;
    const bool diag = ((bj >> 1) == bi);
    #pragma unroll
    for (int m = 0; m < 4; ++m) {
        #pragma unroll
        for (int r = 0; r < 16; ++r) {
            // C/D layout: col = lane&31, row = (r&3) + 8*(r>>2) + 4*(lane>>5)
            const int I = itb + m * 32 + (r & 3) + ((r >> 2) << 3) + (lh << 2);
            const float sqi = sq[I];
            const float wi  = ((int)sub[I] == 0) ? w0 : w1;
            #pragma unroll
            for (int n = 0; n < 2; ++n) {
                const float g = acc[m][n][r];
                float l2 = fmaxf(sqi + sqJ[n] - 2.f * g, 0.f);
                const float tt  = exp2f(l2 * c2);           // exp(-L2/(16*bw))
                const float t2  = tt * tt;
                const float t4  = t2 * t2;
                const float t8  = t4 * t4;
                const float t16 = t8 * t8;
                const float K   = tt + t2 + t4 + t8 + t16;
                float f = 2.f;
                if (diag) {
                    const int J = jtb + n * 32 + ln;
                    f = (I < J) ? 2.f : ((I == J) ? 1.f : 0.f);
                }
                part += f * wi * wJ[n] * K;
            }
        }
    }

    // block reduction (reuse LDS; all tile reads are behind the final barrier)
    float* red = (float*)lds;
    red[t] = part;
    __syncthreads();
    #pragma unroll
    for (int s = 128; s; s >>= 1) {
        if (t < s) red[t] += red[t + s];
        __syncthreads();
    }
    if (t == 0) atomicAdd(&sc->result, (double)red[0]);
}

// ---------------------------------------------------------------- K4: emit scalar
__global__ void k4_write(const Scalars* sc, float* out) {
    if (threadIdx.x == 0) out[0] = (float)sc->result;
}

extern "C" void kernel_launch(void* const* d_in, const int* in_sizes, int n_in,
                              void* d_out, int out_size, void* d_ws, size_t ws_size,
                              hipStream_t stream) {
    const long long* sub = (const long long*)d_in[0];   // subggroup int64 (N,1)
    const float*     x   = (const float*)d_in[1];       // outputs fp32 (N,256)
    float* out = (float*)d_out;

    char* ws = (char*)d_ws;
    float*          sq     = (float*)ws;
    float*          colsum = (float*)(ws + 32768);
    Scalars*        sc     = (Scalars*)(ws + 33792);
    unsigned short* plane  = (unsigned short*)(ws + 36864);   // 4 MB fp16 plane

    // zero the accumulators (colsum + scalars); sq/plane fully overwritten
    hipMemsetAsync(ws + 32768, 0, 2048, stream);

    k1_rows<<<N_ROWS / 32, 256, 0, stream>>>(x, sub, sq, colsum, plane, sc);
    k2_scalars<<<1, 64, 0, stream>>>(colsum, sc);

    dim3 g3(N_ROWS / 128, N_ROWS / 256);
    k3_mmd<<<g3, 256, 0, stream>>>(plane, sub, sq, sc);

    k4_write<<<1, 64, 0, stream>>>(sc, out);
}